// Round 26
// baseline (383.613 us; speedup 1.0000x reference)
//
#include <hip/hip_runtime.h>
#include <math.h>

#define NT 256
#define NTS 128   // sage_layer: 2 waves, 16-node tile

typedef unsigned short ushort_t;
typedef unsigned int uint_t;
typedef __attribute__((ext_vector_type(8))) short bf16x8;
typedef __attribute__((ext_vector_type(4))) float f32x4;

__device__ __forceinline__ int rli(int v, int l) {
    return __builtin_amdgcn_readlane(v, l);
}
__device__ __forceinline__ int imax(int a, int b) { return a > b ? a : b; }
__device__ __forceinline__ int imin(int a, int b) { return a < b ? a : b; }

__device__ __forceinline__ ushort_t f2bf_rne(float f) {
    uint_t u = __float_as_uint(f);
    uint_t r = u + 0x7FFF + ((u >> 16) & 1);
    return (ushort_t)(r >> 16);
}
__device__ __forceinline__ float bf2f(ushort_t b) {
    return __uint_as_float(((uint_t)b) << 16);
}
__device__ __forceinline__ float rlf(float v, int l) {
    return __int_as_float(__builtin_amdgcn_readlane(__float_as_int(v), l));
}

// ---------------- CSR build ----------------

__global__ void zero_i32(int* __restrict__ p, int n) {
    int t = blockIdx.x * blockDim.x + threadIdx.x;
    if (t < n) p[t] = 0;
}

__global__ void hist_dst(int* __restrict__ cnt, const int* __restrict__ dst, int n_edges) {
    int e = blockIdx.x * blockDim.x + threadIdx.x;
    if (e < n_edges) atomicAdd(&cnt[dst[e]], 1);
}

__global__ void scan_blocks(const int* __restrict__ cnt, int* __restrict__ bsum, int n) {
    __shared__ int s[NT];
    int i = blockIdx.x * NT + threadIdx.x;
    s[threadIdx.x] = (i < n) ? cnt[i] : 0;
    __syncthreads();
    for (int off = NT / 2; off > 0; off >>= 1) {
        if (threadIdx.x < off) s[threadIdx.x] += s[threadIdx.x + off];
        __syncthreads();
    }
    if (threadIdx.x == 0) bsum[blockIdx.x] = s[0];
}

__global__ void scan_bsum(const int* __restrict__ bsum, int* __restrict__ boff,
                          int nb, int* __restrict__ row_off, int n) {
    __shared__ int s[1024];
    int tid = threadIdx.x;
    int v = (tid < nb) ? bsum[tid] : 0;
    s[tid] = v;
    __syncthreads();
    for (int off = 1; off < 1024; off <<= 1) {
        int t = (tid >= off) ? s[tid - off] : 0;
        __syncthreads();
        s[tid] += t;
        __syncthreads();
    }
    if (tid < nb) boff[tid] = s[tid] - v;
    if (tid == nb - 1) row_off[n] = s[tid];
}

__global__ void scan_final(const int* __restrict__ cnt, const int* __restrict__ boff,
                           int* __restrict__ row_off, int* __restrict__ cursor, int n) {
    __shared__ int s[NT];
    int i = blockIdx.x * NT + threadIdx.x;
    int v = (i < n) ? cnt[i] : 0;
    s[threadIdx.x] = v;
    __syncthreads();
    for (int off = 1; off < NT; off <<= 1) {
        int t = (threadIdx.x >= off) ? s[threadIdx.x - off] : 0;
        __syncthreads();
        s[threadIdx.x] += t;
        __syncthreads();
    }
    if (i < n) {
        int ex = boff[blockIdx.x] + s[threadIdx.x] - v;
        row_off[i] = ex;
        cursor[i] = ex;
    }
}

__global__ void edge_scatter(int* __restrict__ csr_src, int* __restrict__ cursor,
                             const int* __restrict__ src, const int* __restrict__ dst,
                             int n_edges) {
    int e = blockIdx.x * blockDim.x + threadIdx.x;
    if (e < n_edges) {
        int p = atomicAdd(&cursor[dst[e]], 1);
        csr_src[p] = src[e];
    }
}

// ---------------- merged prep: bf16(x) + pack both W + pool init ----------------
__device__ __forceinline__ ushort_t pack_one(int t, const float* Wl, const float* Wr) {
    int i = t & 7;
    int lane = (t >> 3) & 63;
    int nt = (t >> 9) & 3;
    int ks = t >> 11;
    int k = ks * 32 + ((lane >> 4) << 3) + i;
    int f = nt * 16 + (lane & 15);
    float w = (k < 64) ? Wl[f * 64 + k] : Wr[f * 64 + (k - 64)];
    return f2bf_rne(w);
}

__global__ void prep(ushort_t* __restrict__ bfX, const float* __restrict__ x, int nfeat,
                     ushort_t* __restrict__ pw0, const float* __restrict__ Wl0,
                     const float* __restrict__ Wr0,
                     ushort_t* __restrict__ pw, const float* __restrict__ Wl,
                     const float* __restrict__ Wr,
                     float* __restrict__ pooled) {
    int t = blockIdx.x * NT + threadIdx.x;
    int stride = gridDim.x * NT;
    for (int i = t; i < nfeat; i += stride) bfX[i] = f2bf_rne(x[i]);
    for (int i = t; i < 8192; i += stride) {
        pw0[i] = pack_one(i, Wl0, Wr0);
        pw[i] = pack_one(i, Wl, Wr);
        pooled[i] = -INFINITY;
    }
}

// ---------------- pooling helper ----------------

__device__ __forceinline__ void atomicMaxFloat(float* addr, float value) {
    if (value >= 0.0f)
        atomicMax((int*)addr, __float_as_int(value));
    else
        atomicMin((unsigned int*)addr, (unsigned int)__float_as_int(value));
}

// ---------------- gather for one node (4 edges per load) ----------------
// Quarter-wave mapping: 16 lanes x uint2 (8B) cover one 128B bf16 row, so
// each load fetches 4 edges' rows. Combine via shfl_xor(16,32); lanes 0-15
// write the mean row (features 4*l15..+3) into A.
__device__ __forceinline__ void gather_node(
    ushort_t* __restrict__ A, int row, bool ok, int idx, int b, int d,
    const uint2* __restrict__ hb8, const ushort_t* __restrict__ hb_in,
    const int* __restrict__ csr_src, int lane, int l15, int q) {
    int dm1 = imax(d - 1, 0);
    if (ok && d <= 64) {
        float a0 = 0.f, a1 = 0.f, a2 = 0.f, a3 = 0.f;
        for (int jj = 0; jj < d; jj += 32) {
            uint2 w0, w1, w2, w3, w4, w5, w6, w7;
#define LD(L, W)                                                              \
            {                                                                 \
                int p0 = imin(jj + 4 * (L) + 0, dm1);                         \
                int p1 = imin(jj + 4 * (L) + 1, dm1);                         \
                int p2 = imin(jj + 4 * (L) + 2, dm1);                         \
                int p3 = imin(jj + 4 * (L) + 3, dm1);                         \
                int r0 = rli(idx, p0), r1 = rli(idx, p1);                     \
                int r2 = rli(idx, p2), r3 = rli(idx, p3);                     \
                int is = q < 2 ? (q == 0 ? r0 : r1) : (q == 2 ? r2 : r3);     \
                W = hb8[((size_t)(unsigned)is << 4) + l15];                   \
            }
            LD(0, w0) LD(1, w1) LD(2, w2) LD(3, w3)
            LD(4, w4) LD(5, w5) LD(6, w6) LD(7, w7)
#undef LD
#define CS(L, W)                                                              \
            {                                                                 \
                float f = ((jj + 4 * (L) + q) < d) ? 1.f : 0.f;               \
                a0 += f * __uint_as_float((W).x << 16);                       \
                a1 += f * __uint_as_float((W).x & 0xffff0000u);               \
                a2 += f * __uint_as_float((W).y << 16);                       \
                a3 += f * __uint_as_float((W).y & 0xffff0000u);               \
            }
            CS(0, w0) CS(1, w1) CS(2, w2) CS(3, w3)
            CS(4, w4) CS(5, w5) CS(6, w6) CS(7, w7)
#undef CS
        }
        a0 += __shfl_xor(a0, 16); a0 += __shfl_xor(a0, 32);
        a1 += __shfl_xor(a1, 16); a1 += __shfl_xor(a1, 32);
        a2 += __shfl_xor(a2, 16); a2 += __shfl_xor(a2, 32);
        a3 += __shfl_xor(a3, 16); a3 += __shfl_xor(a3, 32);
        float inv = 1.0f / (float)imax(d, 1);
        if (lane < 16) {
            uint_t m0 = (uint_t)f2bf_rne(a0 * inv) |
                        ((uint_t)f2bf_rne(a1 * inv) << 16);
            uint_t m1 = (uint_t)f2bf_rne(a2 * inv) |
                        ((uint_t)f2bf_rne(a3 * inv) << 16);
            *(uint_t*)&A[row * 136 + 4 * l15] = m0;
            *(uint_t*)&A[row * 136 + 4 * l15 + 2] = m1;
        }
    } else if (ok) {
        // slow path: deg > 64, chunked per-lane (feature = lane)
        float aa = 0.f;
        int e_ = b + d;
        for (int cb = b; cb < e_; cb += 64) {
            int m = e_ - cb; if (m > 64) m = 64;
            int lidx = cb + (lane < m ? lane : m - 1);
            int idx2 = csr_src[lidx];
            for (int j = 0; j < m; ++j)
                aa += bf2f(hb_in[((size_t)(unsigned)rli(idx2, j) << 6) + lane]);
        }
        A[row * 136 + lane] = f2bf_rne(aa * (1.0f / (float)imax(d, 1)));
    } else {
        A[row * 136 + lane] = 0;
    }
}

// ---------------- fused SAGE layer: 4-edges-per-load gather + MFMA dense ----------------
__global__ __launch_bounds__(NTS, 8) void sage_layer(
    ushort_t* __restrict__ out_bf, float* __restrict__ pooled,
    const ushort_t* __restrict__ hb_in,
    const int* __restrict__ row_off, const int* __restrict__ csr_src,
    const int* __restrict__ batch,
    const ushort_t* __restrict__ pw,
    const float* __restrict__ bl,
    int n_nodes, int do_pool) {
    __shared__ ushort_t A[16 * 136];
    int tid = threadIdx.x;
    int lane = tid & 63;
    int v = tid >> 6;  // wave 0..1
    int g0 = blockIdx.x * 16 + v * 8;
    int l15 = lane & 15;
    int q = lane >> 4;  // quarter 0..3
    const uint2* hb8 = (const uint2*)hb_in;  // row = 16 uint2

    int roidx = imin(g0 + imin(lane, 8), n_nodes);
    int ro = row_off[roidx];

    int b0 = rli(ro, 0), b1 = rli(ro, 1), b2 = rli(ro, 2), b3 = rli(ro, 3);
    int b4 = rli(ro, 4), b5 = rli(ro, 5), b6 = rli(ro, 6), b7 = rli(ro, 7);
    int e8 = rli(ro, 8);
    int d0 = b1 - b0, d1 = b2 - b1, d2 = b3 - b2, d3 = b4 - b3;
    int d4 = b5 - b4, d5 = b6 - b5, d6 = b7 - b6, d7 = e8 - b7;

    // ---- hoisted independent loads: 8 idx vectors + 8 hv rows ----
#define IDXLD(N) int idx##N = csr_src[b##N + (lane < d##N ? lane : imax(d##N - 1, 0))];
    IDXLD(0) IDXLD(1) IDXLD(2) IDXLD(3) IDXLD(4) IDXLD(5) IDXLD(6) IDXLD(7)
#undef IDXLD
#define HVLD(N) ushort_t hv##N = (g0 + (N) < n_nodes) \
        ? hb_in[((size_t)(g0 + (N)) << 6) + lane] : (ushort_t)0;
    HVLD(0) HVLD(1) HVLD(2) HVLD(3) HVLD(4) HVLD(5) HVLD(6) HVLD(7)
#undef HVLD
    {
        int rb = v * 8;
        A[(rb + 0) * 136 + 64 + lane] = hv0;
        A[(rb + 1) * 136 + 64 + lane] = hv1;
        A[(rb + 2) * 136 + 64 + lane] = hv2;
        A[(rb + 3) * 136 + 64 + lane] = hv3;
        A[(rb + 4) * 136 + 64 + lane] = hv4;
        A[(rb + 5) * 136 + 64 + lane] = hv5;
        A[(rb + 6) * 136 + 64 + lane] = hv6;
        A[(rb + 7) * 136 + 64 + lane] = hv7;
    }

    gather_node(A, v * 8 + 0, g0 + 0 < n_nodes, idx0, b0, d0, hb8, hb_in, csr_src, lane, l15, q);
    gather_node(A, v * 8 + 1, g0 + 1 < n_nodes, idx1, b1, d1, hb8, hb_in, csr_src, lane, l15, q);
    gather_node(A, v * 8 + 2, g0 + 2 < n_nodes, idx2, b2, d2, hb8, hb_in, csr_src, lane, l15, q);
    gather_node(A, v * 8 + 3, g0 + 3 < n_nodes, idx3, b3, d3, hb8, hb_in, csr_src, lane, l15, q);
    gather_node(A, v * 8 + 4, g0 + 4 < n_nodes, idx4, b4, d4, hb8, hb_in, csr_src, lane, l15, q);
    gather_node(A, v * 8 + 5, g0 + 5 < n_nodes, idx5, b5, d5, hb8, hb_in, csr_src, lane, l15, q);
    gather_node(A, v * 8 + 6, g0 + 6 < n_nodes, idx6, b6, d6, hb8, hb_in, csr_src, lane, l15, q);
    gather_node(A, v * 8 + 7, g0 + 7 < n_nodes, idx7, b7, d7, hb8, hb_in, csr_src, lane, l15, q);
    __syncthreads();

    // ---- phase 2: MFMA dense (r20 verbatim) ----
    int a_row = lane & 15;
    int kbase = (lane >> 4) << 3;
#pragma unroll
    for (int p = 0; p < 2; ++p) {
        int nt = v * 2 + p;
        f32x4 acc = {0.f, 0.f, 0.f, 0.f};
#pragma unroll
        for (int ks = 0; ks < 4; ++ks) {
            bf16x8 af = *reinterpret_cast<const bf16x8*>(&A[a_row * 136 + ks * 32 + kbase]);
            bf16x8 bf = *reinterpret_cast<const bf16x8*>(&pw[(((ks << 2) + nt) * 64 + lane) << 3]);
            acc = __builtin_amdgcn_mfma_f32_16x16x32_bf16(af, bf, acc, 0, 0, 0);
        }
        int c = nt * 16 + (lane & 15);
        float bias = bl[c];
        int rbase = blockIdx.x * 16 + ((lane >> 4) << 2);
#pragma unroll
        for (int j = 0; j < 4; ++j) {
            int g = rbase + j;
            if (g < n_nodes) {
                float o = tanhf(acc[j] + bias);
                if (do_pool) {
                    atomicMaxFloat(&pooled[(size_t)batch[g] * 64 + c], o);
                } else {
                    out_bf[(size_t)g * 64 + c] = f2bf_rne(o);
                }
            }
        }
    }
}

// ---------------- MLP head ----------------
__global__ void head(float* __restrict__ out, const float* __restrict__ pooled,
                     const float* __restrict__ W1, const float* __restrict__ b1,
                     const float* __restrict__ W2, const float* __restrict__ b2) {
    __shared__ float W1T[64][64];
    int tid = threadIdx.x;
    for (int t = tid; t < 4096; t += NT) {
        int f = t >> 6, k = t & 63;
        W1T[k][f] = W1[t];
    }
    __syncthreads();

    int lane = tid & 63;
    int g = blockIdx.x * (NT >> 6) + (tid >> 6);
    float v = pooled[(size_t)g * 64 + lane];
    float bias = b1[lane];
#pragma unroll
    for (int it = 0; it < 3; ++it) {
        float acc = bias;
#pragma unroll
        for (int k = 0; k < 64; ++k) {
            acc += rlf(v, k) * W1T[k][lane];
        }
        v = tanhf(acc);
    }
#pragma unroll
    for (int j = 0; j < 3; ++j) {
        float p = v * W2[j * 64 + lane];
#pragma unroll
        for (int off = 32; off >= 1; off >>= 1) p += __shfl_xor(p, off);
        if (lane == 0) out[g * 3 + j] = p + b2[j];
    }
}

// ---------------- launch ----------------

extern "C" void kernel_launch(void* const* d_in, const int* in_sizes, int n_in,
                              void* d_out, int out_size, void* d_ws, size_t ws_size,
                              hipStream_t stream) {
    const float* x   = (const float*)d_in[0];
    const float* Wl0 = (const float*)d_in[1];
    const float* Wr0 = (const float*)d_in[2];
    const float* bl0 = (const float*)d_in[3];
    const float* Wl  = (const float*)d_in[4];
    const float* Wr  = (const float*)d_in[5];
    const float* bl  = (const float*)d_in[6];
    const float* W1  = (const float*)d_in[7];
    const float* b1  = (const float*)d_in[8];
    const float* W2  = (const float*)d_in[9];
    const float* b2  = (const float*)d_in[10];
    const int* ei    = (const int*)d_in[11];
    const int* batch = (const int*)d_in[12];

    int n_nodes = in_sizes[0] / 64;
    int n_edges = in_sizes[11] / 2;
    const int* src = ei;
    const int* dst = ei + n_edges;

    int nb = (n_nodes + NT - 1) / NT;
    size_t nfeat = (size_t)n_nodes * 64;

    int* csr_src  = (int*)d_ws;                           // n_edges
    int* row_off  = csr_src + n_edges;                    // n_nodes+1
    int* cursor   = row_off + (n_nodes + 1);              // n_nodes
    int* cnt      = cursor + n_nodes;                     // n_nodes
    int* bsum     = cnt + n_nodes;                        // nb
    int* boff     = bsum + nb;                            // nb
    float* pooled = (float*)(boff + nb);                  // 128*64
    ushort_t* pw0 = (ushort_t*)(pooled + 128 * 64);       // 8192
    ushort_t* pw  = pw0 + 8192;                           // 8192
    ushort_t* bfX = pw + 8192;                            // nfeat
    ushort_t* bfA = bfX + nfeat;                          // nfeat
    ushort_t* bfB = bfA + nfeat;                          // nfeat

    int eblk = (n_edges + NT - 1) / NT;
    int sage_blk = (n_nodes + 15) / 16;  // 3125

    // CSR build (parallel scan)
    zero_i32<<<nb, NT, 0, stream>>>(cnt, n_nodes);
    hist_dst<<<eblk, NT, 0, stream>>>(cnt, dst, n_edges);
    scan_blocks<<<nb, NT, 0, stream>>>(cnt, bsum, n_nodes);
    scan_bsum<<<1, 1024, 0, stream>>>(bsum, boff, nb, row_off, n_nodes);
    scan_final<<<nb, NT, 0, stream>>>(cnt, boff, row_off, cursor, n_nodes);
    edge_scatter<<<eblk, NT, 0, stream>>>(csr_src, cursor, src, dst, n_edges);

    // merged prep: bf16 x + packed weights + pool init
    prep<<<1024, NT, 0, stream>>>(bfX, x, (int)nfeat, pw0, Wl0, Wr0, pw, Wl, Wr, pooled);

    // layers (all-bf16 inter-layer state)
    sage_layer<<<sage_blk, NTS, 0, stream>>>(bfA, pooled, bfX, row_off, csr_src,
                                             batch, pw0, bl0, n_nodes, 0);
    sage_layer<<<sage_blk, NTS, 0, stream>>>(bfB, pooled, bfA, row_off, csr_src,
                                             batch, pw, bl, n_nodes, 0);
    sage_layer<<<sage_blk, NTS, 0, stream>>>(bfA, pooled, bfB, row_off, csr_src,
                                             batch, pw, bl, n_nodes, 0);
    sage_layer<<<sage_blk, NTS, 0, stream>>>(bfB, pooled, bfA, row_off, csr_src,
                                             batch, pw, bl, n_nodes, 1);

    head<<<32, NT, 0, stream>>>((float*)d_out, pooled, W1, b1, W2, b2);
}

// Round 28
// 380.146 us; speedup vs baseline: 1.0091x; 1.0091x over previous
//
#include <hip/hip_runtime.h>
#include <math.h>

#define NT 256
#define NTS 128   // sage_layer: 2 waves, 16-node tile

typedef unsigned short ushort_t;
typedef unsigned int uint_t;
typedef __attribute__((ext_vector_type(8))) short bf16x8;
typedef __attribute__((ext_vector_type(4))) float f32x4;

__device__ __forceinline__ int rli(int v, int l) {
    return __builtin_amdgcn_readlane(v, l);
}
__device__ __forceinline__ int imax(int a, int b) { return a > b ? a : b; }
__device__ __forceinline__ int imin(int a, int b) { return a < b ? a : b; }

__device__ __forceinline__ ushort_t f2bf_rne(float f) {
    uint_t u = __float_as_uint(f);
    uint_t r = u + 0x7FFF + ((u >> 16) & 1);
    return (ushort_t)(r >> 16);
}
__device__ __forceinline__ float bf2f(ushort_t b) {
    return __uint_as_float(((uint_t)b) << 16);
}
__device__ __forceinline__ float rlf(float v, int l) {
    return __int_as_float(__builtin_amdgcn_readlane(__float_as_int(v), l));
}

// ---------------- CSR build ----------------

__global__ void zero_i32(int* __restrict__ p, int n) {
    int t = blockIdx.x * blockDim.x + threadIdx.x;
    if (t < n) p[t] = 0;
}

__global__ void hist_dst(int* __restrict__ cnt, const int* __restrict__ dst, int n_edges) {
    int e = blockIdx.x * blockDim.x + threadIdx.x;
    if (e < n_edges) atomicAdd(&cnt[dst[e]], 1);
}

__global__ void scan_blocks(const int* __restrict__ cnt, int* __restrict__ bsum, int n) {
    __shared__ int s[NT];
    int i = blockIdx.x * NT + threadIdx.x;
    s[threadIdx.x] = (i < n) ? cnt[i] : 0;
    __syncthreads();
    for (int off = NT / 2; off > 0; off >>= 1) {
        if (threadIdx.x < off) s[threadIdx.x] += s[threadIdx.x + off];
        __syncthreads();
    }
    if (threadIdx.x == 0) bsum[blockIdx.x] = s[0];
}

__global__ void scan_bsum(const int* __restrict__ bsum, int* __restrict__ boff,
                          int nb, int* __restrict__ row_off, int n) {
    __shared__ int s[1024];
    int tid = threadIdx.x;
    int v = (tid < nb) ? bsum[tid] : 0;
    s[tid] = v;
    __syncthreads();
    for (int off = 1; off < 1024; off <<= 1) {
        int t = (tid >= off) ? s[tid - off] : 0;
        __syncthreads();
        s[tid] += t;
        __syncthreads();
    }
    if (tid < nb) boff[tid] = s[tid] - v;
    if (tid == nb - 1) row_off[n] = s[tid];
}

__global__ void scan_final(const int* __restrict__ cnt, const int* __restrict__ boff,
                           int* __restrict__ row_off, int* __restrict__ cursor, int n) {
    __shared__ int s[NT];
    int i = blockIdx.x * NT + threadIdx.x;
    int v = (i < n) ? cnt[i] : 0;
    s[threadIdx.x] = v;
    __syncthreads();
    for (int off = 1; off < NT; off <<= 1) {
        int t = (threadIdx.x >= off) ? s[threadIdx.x - off] : 0;
        __syncthreads();
        s[threadIdx.x] += t;
        __syncthreads();
    }
    if (i < n) {
        int ex = boff[blockIdx.x] + s[threadIdx.x] - v;
        row_off[i] = ex;
        cursor[i] = ex;
    }
}

__global__ void edge_scatter(int* __restrict__ csr_src, int* __restrict__ cursor,
                             const int* __restrict__ src, const int* __restrict__ dst,
                             int n_edges) {
    int e = blockIdx.x * blockDim.x + threadIdx.x;
    if (e < n_edges) {
        int p = atomicAdd(&cursor[dst[e]], 1);
        csr_src[p] = src[e];
    }
}

// ---------------- merged prep: bf16(x) + pack both W + pool init ----------------
__device__ __forceinline__ ushort_t pack_one(int t, const float* Wl, const float* Wr) {
    int i = t & 7;
    int lane = (t >> 3) & 63;
    int nt = (t >> 9) & 3;
    int ks = t >> 11;
    int k = ks * 32 + ((lane >> 4) << 3) + i;
    int f = nt * 16 + (lane & 15);
    float w = (k < 64) ? Wl[f * 64 + k] : Wr[f * 64 + (k - 64)];
    return f2bf_rne(w);
}

__global__ void prep(ushort_t* __restrict__ bfX, const float* __restrict__ x, int nfeat,
                     ushort_t* __restrict__ pw0, const float* __restrict__ Wl0,
                     const float* __restrict__ Wr0,
                     ushort_t* __restrict__ pw, const float* __restrict__ Wl,
                     const float* __restrict__ Wr,
                     float* __restrict__ pooled) {
    int t = blockIdx.x * NT + threadIdx.x;
    int stride = gridDim.x * NT;
    for (int i = t; i < nfeat; i += stride) bfX[i] = f2bf_rne(x[i]);
    for (int i = t; i < 8192; i += stride) {
        pw0[i] = pack_one(i, Wl0, Wr0);
        pw[i] = pack_one(i, Wl, Wr);
        pooled[i] = -INFINITY;
    }
}

// ---------------- pooling helper ----------------

__device__ __forceinline__ void atomicMaxFloat(float* addr, float value) {
    if (value >= 0.0f)
        atomicMax((int*)addr, __float_as_int(value));
    else
        atomicMin((unsigned int*)addr, (unsigned int)__float_as_int(value));
}

// ---------------- single-node gather (r24 2-edge-per-load), d <= 64 or slow ----------------
__device__ __forceinline__ void gather_node(
    ushort_t* __restrict__ A, int row, bool ok, int idx, int b, int d,
    const uint_t* __restrict__ hb32, const ushort_t* __restrict__ hb_in,
    const int* __restrict__ csr_src, int lane, int l31, int h) {
    int dm1 = imax(d - 1, 0);
    if (ok && d <= 64) {
        float accLo = 0.f, accHi = 0.f;
        for (int jj = 0; jj < d; jj += 16) {
            uint_t w0, w1, w2, w3, w4, w5, w6, w7;
#define LD(L, W)                                                              \
            {                                                                 \
                int eA = imin(jj + 2 * (L), dm1);                             \
                int eB = imin(jj + 2 * (L) + 1, dm1);                         \
                int is = (lane < 32) ? rli(idx, eA) : rli(idx, eB);           \
                W = hb32[((size_t)(unsigned)is << 5) + l31];                  \
            }
            LD(0, w0) LD(1, w1) LD(2, w2) LD(3, w3)
            LD(4, w4) LD(5, w5) LD(6, w6) LD(7, w7)
#undef LD
#define CS(L, W)                                                              \
            {                                                                 \
                float f = ((jj + 2 * (L) + h) < d) ? 1.f : 0.f;               \
                accLo += f * __uint_as_float((W) << 16);                      \
                accHi += f * __uint_as_float((W) & 0xffff0000u);              \
            }
            CS(0, w0) CS(1, w1) CS(2, w2) CS(3, w3)
            CS(4, w4) CS(5, w5) CS(6, w6) CS(7, w7)
#undef CS
        }
        accLo += __shfl_xor(accLo, 32);
        accHi += __shfl_xor(accHi, 32);
        float inv = 1.0f / (float)imax(d, 1);
        if (lane < 32) {
            uint_t mw = (uint_t)f2bf_rne(accLo * inv) |
                        ((uint_t)f2bf_rne(accHi * inv) << 16);
            *(uint_t*)&A[row * 136 + 2 * l31] = mw;
        }
    } else if (ok) {
        float aa = 0.f;
        int e_ = b + d;
        for (int cb = b; cb < e_; cb += 64) {
            int m = e_ - cb; if (m > 64) m = 64;
            int lidx = cb + (lane < m ? lane : m - 1);
            int idx2 = csr_src[lidx];
            for (int j = 0; j < m; ++j)
                aa += bf2f(hb_in[((size_t)(unsigned)rli(idx2, j) << 6) + lane]);
        }
        A[row * 136 + lane] = f2bf_rne(aa * (1.0f / (float)imax(d, 1)));
    } else {
        A[row * 136 + lane] = 0;
    }
}

// ---------------- pair gather: both nodes deg <= 64, 16 loads in flight ----------------
// Loops jj to max(dA,dB) step 16. Per iteration: issue node A's 8 loads,
// then node B's 8 (16 outstanding), consume A (vmcnt leaves B in flight),
// consume B. Wave-uniform doA/doB guards. FIXED vs r27: the jj-loop exists,
// so all d <= 64 edges are covered (r27 truncated at 16).
__device__ __forceinline__ void gather_pair(
    ushort_t* __restrict__ A, int rowA, int idxA, int dA,
    int rowB, int idxB, int dB,
    const uint_t* __restrict__ hb32, int lane, int l31, int h) {
    int dmA = imax(dA - 1, 0), dmB = imax(dB - 1, 0);
    int gmax = imax(dA, dB);
    float loA = 0.f, hiA = 0.f, loB = 0.f, hiB = 0.f;
    for (int jj = 0; jj < gmax; jj += 16) {
        uint_t a0, a1, a2, a3, a4, a5, a6, a7;
        uint_t b0, b1, b2, b3, b4, b5, b6, b7;
        bool doA = jj < dA, doB = jj < dB;
#define LDP(W, IDX, DM, L)                                                    \
        {                                                                     \
            int eA = imin(jj + 2 * (L), DM);                                  \
            int eB = imin(jj + 2 * (L) + 1, DM);                              \
            int is = (lane < 32) ? rli(IDX, eA) : rli(IDX, eB);               \
            W = hb32[((size_t)(unsigned)is << 5) + l31];                      \
        }
        if (doA) {
            LDP(a0, idxA, dmA, 0) LDP(a1, idxA, dmA, 1)
            LDP(a2, idxA, dmA, 2) LDP(a3, idxA, dmA, 3)
            LDP(a4, idxA, dmA, 4) LDP(a5, idxA, dmA, 5)
            LDP(a6, idxA, dmA, 6) LDP(a7, idxA, dmA, 7)
        }
        if (doB) {
            LDP(b0, idxB, dmB, 0) LDP(b1, idxB, dmB, 1)
            LDP(b2, idxB, dmB, 2) LDP(b3, idxB, dmB, 3)
            LDP(b4, idxB, dmB, 4) LDP(b5, idxB, dmB, 5)
            LDP(b6, idxB, dmB, 6) LDP(b7, idxB, dmB, 7)
        }
#undef LDP
#define CSP(ACC_LO, ACC_HI, W, D, L)                                          \
        {                                                                     \
            float f = ((jj + 2 * (L) + h) < (D)) ? 1.f : 0.f;                 \
            ACC_LO += f * __uint_as_float((W) << 16);                         \
            ACC_HI += f * __uint_as_float((W) & 0xffff0000u);                 \
        }
        if (doA) {
            CSP(loA, hiA, a0, dA, 0) CSP(loA, hiA, a1, dA, 1)
            CSP(loA, hiA, a2, dA, 2) CSP(loA, hiA, a3, dA, 3)
            CSP(loA, hiA, a4, dA, 4) CSP(loA, hiA, a5, dA, 5)
            CSP(loA, hiA, a6, dA, 6) CSP(loA, hiA, a7, dA, 7)
        }
        if (doB) {
            CSP(loB, hiB, b0, dB, 0) CSP(loB, hiB, b1, dB, 1)
            CSP(loB, hiB, b2, dB, 2) CSP(loB, hiB, b3, dB, 3)
            CSP(loB, hiB, b4, dB, 4) CSP(loB, hiB, b5, dB, 5)
            CSP(loB, hiB, b6, dB, 6) CSP(loB, hiB, b7, dB, 7)
        }
#undef CSP
    }
    loA += __shfl_xor(loA, 32);
    hiA += __shfl_xor(hiA, 32);
    loB += __shfl_xor(loB, 32);
    hiB += __shfl_xor(hiB, 32);
    float invA = 1.0f / (float)imax(dA, 1);
    float invB = 1.0f / (float)imax(dB, 1);
    if (lane < 32) {
        uint_t mwA = (uint_t)f2bf_rne(loA * invA) |
                     ((uint_t)f2bf_rne(hiA * invA) << 16);
        uint_t mwB = (uint_t)f2bf_rne(loB * invB) |
                     ((uint_t)f2bf_rne(hiB * invB) << 16);
        *(uint_t*)&A[rowA * 136 + 2 * l31] = mwA;
        *(uint_t*)&A[rowB * 136 + 2 * l31] = mwB;
    }
}

// ---------------- fused SAGE layer: pair-interleaved gather + MFMA dense ----------------
__global__ __launch_bounds__(NTS, 8) void sage_layer(
    ushort_t* __restrict__ out_bf, float* __restrict__ pooled,
    const ushort_t* __restrict__ hb_in,
    const int* __restrict__ row_off, const int* __restrict__ csr_src,
    const int* __restrict__ batch,
    const ushort_t* __restrict__ pw,
    const float* __restrict__ bl,
    int n_nodes, int do_pool) {
    __shared__ ushort_t A[16 * 136];
    int tid = threadIdx.x;
    int lane = tid & 63;
    int v = tid >> 6;  // wave 0..1
    int g0 = blockIdx.x * 16 + v * 8;
    int l31 = lane & 31;
    int h = lane >> 5;
    const uint_t* hb32 = (const uint_t*)hb_in;

    int roidx = imin(g0 + imin(lane, 8), n_nodes);
    int ro = row_off[roidx];

    int b0 = rli(ro, 0), b1 = rli(ro, 1), b2 = rli(ro, 2), b3 = rli(ro, 3);
    int b4 = rli(ro, 4), b5 = rli(ro, 5), b6 = rli(ro, 6), b7 = rli(ro, 7);
    int e8 = rli(ro, 8);
    int d0 = b1 - b0, d1 = b2 - b1, d2 = b3 - b2, d3 = b4 - b3;
    int d4 = b5 - b4, d5 = b6 - b5, d6 = b7 - b6, d7 = e8 - b7;

    // ---- hoisted independent loads: 8 idx vectors + 8 hv rows (r24-proven) ----
#define IDXLD(N) int idx##N = csr_src[b##N + (lane < d##N ? lane : imax(d##N - 1, 0))];
    IDXLD(0) IDXLD(1) IDXLD(2) IDXLD(3) IDXLD(4) IDXLD(5) IDXLD(6) IDXLD(7)
#undef IDXLD
#define HVLD(N) ushort_t hv##N = (g0 + (N) < n_nodes) \
        ? hb_in[((size_t)(g0 + (N)) << 6) + lane] : (ushort_t)0;
    HVLD(0) HVLD(1) HVLD(2) HVLD(3) HVLD(4) HVLD(5) HVLD(6) HVLD(7)
#undef HVLD
    {
        int rb = v * 8;
        A[(rb + 0) * 136 + 64 + lane] = hv0;
        A[(rb + 1) * 136 + 64 + lane] = hv1;
        A[(rb + 2) * 136 + 64 + lane] = hv2;
        A[(rb + 3) * 136 + 64 + lane] = hv3;
        A[(rb + 4) * 136 + 64 + lane] = hv4;
        A[(rb + 5) * 136 + 64 + lane] = hv5;
        A[(rb + 6) * 136 + 64 + lane] = hv6;
        A[(rb + 7) * 136 + 64 + lane] = hv7;
    }

    // ---- pair-interleaved gather: (0,1),(2,3),(4,5),(6,7) ----
#define PAIR(NA, NB)                                                          \
    {                                                                         \
        bool okA = (g0 + (NA)) < n_nodes;                                     \
        bool okB = (g0 + (NB)) < n_nodes;                                     \
        if (okA && okB && d##NA <= 64 && d##NB <= 64) {                       \
            gather_pair(A, v * 8 + (NA), idx##NA, d##NA,                      \
                        v * 8 + (NB), idx##NB, d##NB, hb32, lane, l31, h);    \
        } else {                                                              \
            gather_node(A, v * 8 + (NA), okA, idx##NA, b##NA, d##NA,          \
                        hb32, hb_in, csr_src, lane, l31, h);                  \
            gather_node(A, v * 8 + (NB), okB, idx##NB, b##NB, d##NB,          \
                        hb32, hb_in, csr_src, lane, l31, h);                  \
        }                                                                     \
    }
    PAIR(0, 1) PAIR(2, 3) PAIR(4, 5) PAIR(6, 7)
#undef PAIR
    __syncthreads();

    // ---- phase 2: MFMA dense (r20 verbatim) ----
    int a_row = lane & 15;
    int kbase = (lane >> 4) << 3;
#pragma unroll
    for (int p = 0; p < 2; ++p) {
        int nt = v * 2 + p;
        f32x4 acc = {0.f, 0.f, 0.f, 0.f};
#pragma unroll
        for (int ks = 0; ks < 4; ++ks) {
            bf16x8 af = *reinterpret_cast<const bf16x8*>(&A[a_row * 136 + ks * 32 + kbase]);
            bf16x8 bf = *reinterpret_cast<const bf16x8*>(&pw[(((ks << 2) + nt) * 64 + lane) << 3]);
            acc = __builtin_amdgcn_mfma_f32_16x16x32_bf16(af, bf, acc, 0, 0, 0);
        }
        int c = nt * 16 + (lane & 15);
        float bias = bl[c];
        int rbase = blockIdx.x * 16 + ((lane >> 4) << 2);
#pragma unroll
        for (int j = 0; j < 4; ++j) {
            int g = rbase + j;
            if (g < n_nodes) {
                float o = tanhf(acc[j] + bias);
                if (do_pool) {
                    atomicMaxFloat(&pooled[(size_t)batch[g] * 64 + c], o);
                } else {
                    out_bf[(size_t)g * 64 + c] = f2bf_rne(o);
                }
            }
        }
    }
}

// ---------------- MLP head ----------------
__global__ void head(float* __restrict__ out, const float* __restrict__ pooled,
                     const float* __restrict__ W1, const float* __restrict__ b1,
                     const float* __restrict__ W2, const float* __restrict__ b2) {
    __shared__ float W1T[64][64];
    int tid = threadIdx.x;
    for (int t = tid; t < 4096; t += NT) {
        int f = t >> 6, k = t & 63;
        W1T[k][f] = W1[t];
    }
    __syncthreads();

    int lane = tid & 63;
    int g = blockIdx.x * (NT >> 6) + (tid >> 6);
    float v = pooled[(size_t)g * 64 + lane];
    float bias = b1[lane];
#pragma unroll
    for (int it = 0; it < 3; ++it) {
        float acc = bias;
#pragma unroll
        for (int k = 0; k < 64; ++k) {
            acc += rlf(v, k) * W1T[k][lane];
        }
        v = tanhf(acc);
    }
#pragma unroll
    for (int j = 0; j < 3; ++j) {
        float p = v * W2[j * 64 + lane];
#pragma unroll
        for (int off = 32; off >= 1; off >>= 1) p += __shfl_xor(p, off);
        if (lane == 0) out[g * 3 + j] = p + b2[j];
    }
}

// ---------------- launch ----------------

extern "C" void kernel_launch(void* const* d_in, const int* in_sizes, int n_in,
                              void* d_out, int out_size, void* d_ws, size_t ws_size,
                              hipStream_t stream) {
    const float* x   = (const float*)d_in[0];
    const float* Wl0 = (const float*)d_in[1];
    const float* Wr0 = (const float*)d_in[2];
    const float* bl0 = (const float*)d_in[3];
    const float* Wl  = (const float*)d_in[4];
    const float* Wr  = (const float*)d_in[5];
    const float* bl  = (const float*)d_in[6];
    const float* W1  = (const float*)d_in[7];
    const float* b1  = (const float*)d_in[8];
    const float* W2  = (const float*)d_in[9];
    const float* b2  = (const float*)d_in[10];
    const int* ei    = (const int*)d_in[11];
    const int* batch = (const int*)d_in[12];

    int n_nodes = in_sizes[0] / 64;
    int n_edges = in_sizes[11] / 2;
    const int* src = ei;
    const int* dst = ei + n_edges;

    int nb = (n_nodes + NT - 1) / NT;
    size_t nfeat = (size_t)n_nodes * 64;

    int* csr_src  = (int*)d_ws;                           // n_edges
    int* row_off  = csr_src + n_edges;                    // n_nodes+1
    int* cursor   = row_off + (n_nodes + 1);              // n_nodes
    int* cnt      = cursor + n_nodes;                     // n_nodes
    int* bsum     = cnt + n_nodes;                        // nb
    int* boff     = bsum + nb;                            // nb
    float* pooled = (float*)(boff + nb);                  // 128*64
    ushort_t* pw0 = (ushort_t*)(pooled + 128 * 64);       // 8192
    ushort_t* pw  = pw0 + 8192;                           // 8192
    ushort_t* bfX = pw + 8192;                            // nfeat
    ushort_t* bfA = bfX + nfeat;                          // nfeat
    ushort_t* bfB = bfA + nfeat;                          // nfeat

    int eblk = (n_edges + NT - 1) / NT;
    int sage_blk = (n_nodes + 15) / 16;  // 3125

    // CSR build (parallel scan)
    zero_i32<<<nb, NT, 0, stream>>>(cnt, n_nodes);
    hist_dst<<<eblk, NT, 0, stream>>>(cnt, dst, n_edges);
    scan_blocks<<<nb, NT, 0, stream>>>(cnt, bsum, n_nodes);
    scan_bsum<<<1, 1024, 0, stream>>>(bsum, boff, nb, row_off, n_nodes);
    scan_final<<<nb, NT, 0, stream>>>(cnt, boff, row_off, cursor, n_nodes);
    edge_scatter<<<eblk, NT, 0, stream>>>(csr_src, cursor, src, dst, n_edges);

    // merged prep: bf16 x + packed weights + pool init
    prep<<<1024, NT, 0, stream>>>(bfX, x, (int)nfeat, pw0, Wl0, Wr0, pw, Wl, Wr, pooled);

    // layers (all-bf16 inter-layer state)
    sage_layer<<<sage_blk, NTS, 0, stream>>>(bfA, pooled, bfX, row_off, csr_src,
                                             batch, pw0, bl0, n_nodes, 0);
    sage_layer<<<sage_blk, NTS, 0, stream>>>(bfB, pooled, bfA, row_off, csr_src,
                                             batch, pw, bl, n_nodes, 0);
    sage_layer<<<sage_blk, NTS, 0, stream>>>(bfA, pooled, bfB, row_off, csr_src,
                                             batch, pw, bl, n_nodes, 0);
    sage_layer<<<sage_blk, NTS, 0, stream>>>(bfB, pooled, bfA, row_off, csr_src,
                                             batch, pw, bl, n_nodes, 1);

    head<<<32, NT, 0, stream>>>((float*)d_out, pooled, W1, b1, W2, b2);
}